// Round 5
// baseline (169.405 us; speedup 1.0000x reference)
//
#include <hip/hip_runtime.h>

// CrossHeadProjectionV2: B=1, N=16, T=S=2048, G=1, I=2, M=16.
// out[n,t,s] = sum_m x[m,t,s]*wq[t][m][n]
//            + sum_i kw2[s,i,n] * (sum_m x[m,t,s]*kw1[s,i,m])
//            + x[n,t,s]*kdd[s,n]
// wq folds w+I, qdd diagonal, and the rank-2 q-side update (t-only deps).
//
// Round-5 structure: BARRIER-FREE. Each wave owns a 64-wide s-slab and TT=8
// t-values; x/wq staging is wave-private LDS (producer lanes == consumer
// lanes' wave), so wave-lockstep + in-order DS pipe replaces __syncthreads.
// k-side weight slices live in registers, loaded once per wave.

#define TDIM 2048
#define SDIM 2048
#define TT 8
#define SBLK 256  // per block; 64 per wave

typedef float vf4 __attribute__((ext_vector_type(4)));

// ---- prep: transpose per-s weights to s-minor for coalesced reads ----
// kt1[i*16+m][s] = kw1[s][i][m]; kt2[i*16+n][s] = kw2[s][i][n]; kddt[n][s] = kdd[s][n]
__global__ void chp_prep(const float* __restrict__ kw1, const float* __restrict__ kw2,
                         const float* __restrict__ kdd,
                         float* __restrict__ kt1, float* __restrict__ kt2,
                         float* __restrict__ kddt) {
  int tid = blockIdx.x * blockDim.x + threadIdx.x;  // 0 .. 163839
  if (tid < 65536) {
    int im = tid >> 11, s = tid & 2047;
    kt1[tid] = kw1[s * 32 + im];
  } else if (tid < 131072) {
    int v = tid - 65536;
    int im = v >> 11, s = v & 2047;
    kt2[v] = kw2[s * 32 + im];
  } else if (tid < 163840) {
    int v = tid - 131072;
    int n = v >> 11, s = v & 2047;
    kddt[v] = kdd[s * 16 + n];
  }
}

__device__ __forceinline__ vf4 ld4(const float* p) {
  return *reinterpret_cast<const vf4*>(p);
}
__device__ __forceinline__ void fma4(vf4& d, const vf4& a, const vf4& b) {
  d.x = fmaf(a.x, b.x, d.x); d.y = fmaf(a.y, b.y, d.y);
  d.z = fmaf(a.z, b.z, d.z); d.w = fmaf(a.w, b.w, d.w);
}
__device__ __forceinline__ void fma4s(vf4& d, const vf4& a, float b) {
  d.x = fmaf(a.x, b, d.x); d.y = fmaf(a.y, b, d.y);
  d.z = fmaf(a.z, b, d.z); d.w = fmaf(a.w, b, d.w);
}

template <bool KT>
__global__ __launch_bounds__(256, 3) void chp_main(
    const float* __restrict__ in, const float* __restrict__ w,
    const float* __restrict__ qw1, const float* __restrict__ qw2,
    const float* __restrict__ qdd, const float* __restrict__ kw1,
    const float* __restrict__ kw2, const float* __restrict__ kdd,
    const float* __restrict__ kt1, const float* __restrict__ kt2,
    const float* __restrict__ kddt, float* __restrict__ out) {
  // Wave-private staging: [wave][m][quad] and [wave][m*16+n]. Single-buffered:
  // in-order per-wave DS + program order (reads of t before writes of t+1)
  // makes this race-free with NO barriers.
  __shared__ vf4 x_lds[4][16][16];
  __shared__ float wq_lds[4][256];

  const int tid = threadIdx.x;
  const int wv = tid >> 6;
  const int lane = tid & 63;
  const int j = lane & 3;    // owns n,m rows {4j..4j+3}
  const int qg = lane >> 2;  // s-quad within the wave's 64-slab: 0..15
  const int s0 = blockIdx.x * SBLK + wv * 64 + qg * 4;
  const int t0 = blockIdx.y * TT;
  const int bm = qg;      // wq row this lane builds
  const int bn4 = j * 4;  // wq cols this lane builds

  // ---- per-wave register-resident weights (own 4 rows, own s-quad) ----
  vf4 kt1v[2][4], kt2v[2][4], kdv[4];
  if constexpr (KT) {
#pragma unroll
    for (int i = 0; i < 2; ++i)
#pragma unroll
      for (int k = 0; k < 4; ++k) {
        kt1v[i][k] = ld4(kt1 + (size_t)(i * 16 + 4 * j + k) * SDIM + s0);
        kt2v[i][k] = ld4(kt2 + (size_t)(i * 16 + 4 * j + k) * SDIM + s0);
      }
#pragma unroll
    for (int k = 0; k < 4; ++k) kdv[k] = ld4(kddt + (size_t)(4 * j + k) * SDIM + s0);
  } else {
#pragma unroll
    for (int i = 0; i < 2; ++i)
#pragma unroll
      for (int k = 0; k < 4; ++k)
#pragma unroll
        for (int c = 0; c < 4; ++c) {
          kt1v[i][k][c] = kw1[(size_t)(s0 + c) * 32 + i * 16 + 4 * j + k];
          kt2v[i][k][c] = kw2[(size_t)(s0 + c) * 32 + i * 16 + 4 * j + k];
        }
#pragma unroll
    for (int k = 0; k < 4; ++k)
#pragma unroll
      for (int c = 0; c < 4; ++c) kdv[k][c] = kdd[(size_t)(s0 + c) * 16 + 4 * j + k];
  }
  const vf4 wrow = ld4(w + bm * 16 + bn4);  // static w row, resident

  vf4 xp[4];          // prefetched x rows (t+1 relative to compute)
  float q1a, q1b, qdq;
  vf4 q2a, q2b;

  auto prefetch = [&](int t) {
#pragma unroll
    for (int k = 0; k < 4; ++k)
      xp[k] = ld4(in + ((size_t)(4 * j + k) * TDIM + t) * SDIM + s0);
    q1a = qw1[t * 32 + bm];
    q1b = qw1[t * 32 + 16 + bm];
    q2a = ld4(qw2 + t * 32 + bn4);
    q2b = ld4(qw2 + t * 32 + 16 + bn4);
    qdq = qdd[t * 16 + bm];
  };
  auto stage = [&]() {
#pragma unroll
    for (int k = 0; k < 4; ++k) x_lds[wv][4 * j + k][qg] = xp[k];
    vf4 wqv;
    wqv.x = fmaf(q1a, q2a.x, fmaf(q1b, q2b.x, wrow.x));
    wqv.y = fmaf(q1a, q2a.y, fmaf(q1b, q2b.y, wrow.y));
    wqv.z = fmaf(q1a, q2a.z, fmaf(q1b, q2b.z, wrow.z));
    wqv.w = fmaf(q1a, q2a.w, fmaf(q1b, q2b.w, wrow.w));
    // identity + q-diag, per-component (no dynamic vector index -> no scratch)
    const float dg = 1.0f + qdq;
    wqv.x += (bm == bn4 + 0) ? dg : 0.0f;
    wqv.y += (bm == bn4 + 1) ? dg : 0.0f;
    wqv.z += (bm == bn4 + 2) ? dg : 0.0f;
    wqv.w += (bm == bn4 + 3) ? dg : 0.0f;
    *reinterpret_cast<vf4*>(&wq_lds[wv][lane * 4]) = wqv;
  };

  // ---- prologue ----
  prefetch(t0);
  stage();
  prefetch(t0 + 1);

#pragma unroll
  for (int tt = 0; tt < TT; ++tt) {
    const int t = t0 + tt;

    vf4 acc[4];
    vf4 p0 = (vf4){0.f, 0.f, 0.f, 0.f}, p1 = p0;
#pragma unroll
    for (int r = 0; r < 4; ++r) acc[r] = (vf4){0.f, 0.f, 0.f, 0.f};

#pragma unroll
    for (int m = 0; m < 16; ++m) {
      const vf4 xm = x_lds[wv][m][qg];
      const vf4 wr = *reinterpret_cast<const vf4*>(&wq_lds[wv][m * 16 + 4 * j]);
      fma4s(acc[0], xm, wr.x);
      fma4s(acc[1], xm, wr.y);
      fma4s(acc[2], xm, wr.z);
      fma4s(acc[3], xm, wr.w);
      if ((m >> 2) == j) {  // own rows: hk partials + k-diag
        const int k = m & 3;
        fma4(p0, xm, kt1v[0][k]);
        fma4(p1, xm, kt1v[1][k]);
        fma4(acc[k], xm, kdv[k]);
      }
    }

    // All LDS reads for t are issued; overwrite staging with t+1 (same wave,
    // program order + in-order DS pipe => safe without a barrier), then
    // refill the register prefetch with t+2.
    if (tt + 1 < TT) stage();
    if (tt + 2 < TT) prefetch(t + 2);

    // butterfly over the 4 j-lanes (lanes 4q..4q+3): full hk at every lane
#pragma unroll
    for (int mask = 1; mask <= 2; mask <<= 1) {
      p0.x += __shfl_xor(p0.x, mask); p0.y += __shfl_xor(p0.y, mask);
      p0.z += __shfl_xor(p0.z, mask); p0.w += __shfl_xor(p0.w, mask);
      p1.x += __shfl_xor(p1.x, mask); p1.y += __shfl_xor(p1.y, mask);
      p1.z += __shfl_xor(p1.z, mask); p1.w += __shfl_xor(p1.w, mask);
    }

#pragma unroll
    for (int r = 0; r < 4; ++r) {
      fma4(acc[r], p0, kt2v[0][r]);
      fma4(acc[r], p1, kt2v[1][r]);
      *reinterpret_cast<vf4*>(out + ((size_t)(4 * j + r) * TDIM + t) * SDIM + s0) =
          acc[r];
    }
  }
}

extern "C" void kernel_launch(void* const* d_in, const int* in_sizes, int n_in,
                              void* d_out, int out_size, void* d_ws, size_t ws_size,
                              hipStream_t stream) {
  const float* in = (const float*)d_in[0];
  const float* qw1 = (const float*)d_in[1];
  const float* qw2 = (const float*)d_in[2];
  const float* kw1 = (const float*)d_in[3];
  const float* kw2 = (const float*)d_in[4];
  const float* qdd = (const float*)d_in[5];
  const float* kdd = (const float*)d_in[6];
  const float* w = (const float*)d_in[7];
  float* out = (float*)d_out;
  float* ws = (float*)d_ws;

  const bool useKT = (ws_size >= 163840ull * sizeof(float));
  float* kt1 = ws;
  float* kt2 = ws + 65536;
  float* kddt = ws + 131072;

  dim3 grid(SDIM / SBLK, TDIM / TT);  // (8, 256)
  if (useKT) {
    hipLaunchKernelGGL(chp_prep, dim3(640), dim3(256), 0, stream, kw1, kw2, kdd, kt1,
                       kt2, kddt);
    hipLaunchKernelGGL((chp_main<true>), grid, dim3(256), 0, stream, in, w, qw1, qw2,
                       qdd, kw1, kw2, kdd, kt1, kt2, kddt, out);
  } else {
    hipLaunchKernelGGL((chp_main<false>), grid, dim3(256), 0, stream, in, w, qw1, qw2,
                       qdd, kw1, kw2, kdd, nullptr, nullptr, nullptr, out);
  }
}

// Round 6
// 156.492 us; speedup vs baseline: 1.0825x; 1.0825x over previous
//
#include <hip/hip_runtime.h>

// CrossHeadProjectionV2: B=1, N=16, T=S=2048, G=1, I=2, M=16.
// out[n,t,s] = sum_m x[m,t,s]*wq[t][m][n]
//            + sum_i kw2[s,i,n] * (sum_m x[m,t,s]*kw1[s,i,m])
//            + x[n,t,s]*kdd[s,n]
// wq folds w+I, qdd diagonal, and the rank-2 q-side update (t-only deps).
//
// R6 = R4 (best, 159us) with ONE change: __launch_bounds__(256,2) so the
// register allocator keeps the 20 vf4 of k-side weights resident instead of
// rematerializing their L2 loads every t-iteration (R4/R5 showed VGPR=84,
// proving the spills). Everything else is byte-identical to R4.

#define TDIM 2048
#define SDIM 2048
#define TT 8
#define SBLK 256

typedef float vf4 __attribute__((ext_vector_type(4)));

// ---- prep: transpose per-s weights to s-minor for coalesced reads ----
// kt1[i*16+m][s] = kw1[s][i][m]; kt2[i*16+n][s] = kw2[s][i][n]; kddt[n][s] = kdd[s][n]
__global__ void chp_prep(const float* __restrict__ kw1, const float* __restrict__ kw2,
                         const float* __restrict__ kdd,
                         float* __restrict__ kt1, float* __restrict__ kt2,
                         float* __restrict__ kddt) {
  int tid = blockIdx.x * blockDim.x + threadIdx.x;  // 0 .. 163839
  if (tid < 65536) {
    int im = tid >> 11, s = tid & 2047;
    kt1[tid] = kw1[s * 32 + im];
  } else if (tid < 131072) {
    int v = tid - 65536;
    int im = v >> 11, s = v & 2047;
    kt2[v] = kw2[s * 32 + im];
  } else if (tid < 163840) {
    int v = tid - 131072;
    int n = v >> 11, s = v & 2047;
    kddt[v] = kdd[s * 16 + n];
  }
}

__device__ __forceinline__ vf4 ld4(const float* p) {
  return *reinterpret_cast<const vf4*>(p);
}
__device__ __forceinline__ void fma4(vf4& d, const vf4& a, const vf4& b) {
  d.x = fmaf(a.x, b.x, d.x); d.y = fmaf(a.y, b.y, d.y);
  d.z = fmaf(a.z, b.z, d.z); d.w = fmaf(a.w, b.w, d.w);
}
__device__ __forceinline__ void fma4s(vf4& d, const vf4& a, float b) {
  d.x = fmaf(a.x, b, d.x); d.y = fmaf(a.y, b, d.y);
  d.z = fmaf(a.z, b, d.z); d.w = fmaf(a.w, b, d.w);
}

template <bool KT>
__global__ __launch_bounds__(256, 2) void chp_main(
    const float* __restrict__ in, const float* __restrict__ w,
    const float* __restrict__ qw1, const float* __restrict__ qw2,
    const float* __restrict__ qdd, const float* __restrict__ kw1,
    const float* __restrict__ kw2, const float* __restrict__ kdd,
    const float* __restrict__ kt1, const float* __restrict__ kt2,
    const float* __restrict__ kddt, float* __restrict__ out) {
  // x_lds[buf][m][quad], rows padded to 65 quads to break bank alignment.
  __shared__ vf4 x_lds[2][16][65];
  __shared__ float wq_lds[2][256];

  const int tid = threadIdx.x;
  const int j = tid & 3;        // n-slot: owns n,m in {4j..4j+3}
  const int qg = tid >> 2;      // s-quad within block: 0..63
  const int s0 = blockIdx.x * SBLK + qg * 4;
  const int t0 = blockIdx.y * TT;

  // ---- per-block register weights (own 4 rows, own s-quad) ----
  vf4 kt1v[2][4], kt2v[2][4], kdv[4];
  if constexpr (KT) {
#pragma unroll
    for (int i = 0; i < 2; ++i)
#pragma unroll
      for (int k = 0; k < 4; ++k) {
        kt1v[i][k] = ld4(kt1 + (size_t)(i * 16 + 4 * j + k) * SDIM + s0);
        kt2v[i][k] = ld4(kt2 + (size_t)(i * 16 + 4 * j + k) * SDIM + s0);
      }
#pragma unroll
    for (int k = 0; k < 4; ++k) kdv[k] = ld4(kddt + (size_t)(4 * j + k) * SDIM + s0);
  } else {
#pragma unroll
    for (int i = 0; i < 2; ++i)
#pragma unroll
      for (int k = 0; k < 4; ++k)
#pragma unroll
        for (int c = 0; c < 4; ++c) {
          kt1v[i][k][c] = kw1[(size_t)(s0 + c) * 32 + i * 16 + 4 * j + k];
          kt2v[i][k][c] = kw2[(size_t)(s0 + c) * 32 + i * 16 + 4 * j + k];
        }
#pragma unroll
    for (int k = 0; k < 4; ++k)
#pragma unroll
      for (int c = 0; c < 4; ++c) kdv[k][c] = kdd[(size_t)(s0 + c) * 16 + 4 * j + k];
  }

  // wq-build role of this thread: entry (bm, bn)
  const int bm = tid >> 4, bn = tid & 15;
  const float wbase = w[bm * 16 + bn];

  // ---- prologue: prefetch + stage t0, prefetch t0+1 ----
  vf4 xp[4];
#pragma unroll
  for (int k = 0; k < 4; ++k)
    xp[k] = ld4(in + ((size_t)(4 * j + k) * TDIM + t0) * SDIM + s0);
  float q1a = qw1[t0 * 32 + bm], q1b = qw1[t0 * 32 + 16 + bm];
  float q2a = qw2[t0 * 32 + bn], q2b = qw2[t0 * 32 + 16 + bn];
  float qd = qdd[t0 * 16 + bn];

#pragma unroll
  for (int k = 0; k < 4; ++k) x_lds[0][4 * j + k][qg] = xp[k];
  {
    float v = fmaf(q1a, q2a, wbase);
    v = fmaf(q1b, q2b, v);
    if (bm == bn) v += 1.0f + qd;
    wq_lds[0][tid] = v;
  }
  {  // prefetch t0+1
    const int t1 = t0 + 1;
#pragma unroll
    for (int k = 0; k < 4; ++k)
      xp[k] = ld4(in + ((size_t)(4 * j + k) * TDIM + t1) * SDIM + s0);
    q1a = qw1[t1 * 32 + bm]; q1b = qw1[t1 * 32 + 16 + bm];
    q2a = qw2[t1 * 32 + bn]; q2b = qw2[t1 * 32 + 16 + bn];
    qd = qdd[t1 * 16 + bn];
  }
  __syncthreads();

  int cur = 0;
  for (int tt = 0; tt < TT; ++tt) {
    const int t = t0 + tt;
    const int nxt = cur ^ 1;

    // ---- compute t from LDS buf[cur] ----
    vf4 acc[4];
    vf4 p0 = (vf4){0.f, 0.f, 0.f, 0.f}, p1 = p0;
#pragma unroll
    for (int r = 0; r < 4; ++r) acc[r] = (vf4){0.f, 0.f, 0.f, 0.f};

#pragma unroll
    for (int m = 0; m < 16; ++m) {
      const vf4 xm = x_lds[cur][m][qg];
      const vf4 wr = *reinterpret_cast<const vf4*>(&wq_lds[cur][m * 16 + 4 * j]);
      fma4s(acc[0], xm, wr.x);
      fma4s(acc[1], xm, wr.y);
      fma4s(acc[2], xm, wr.z);
      fma4s(acc[3], xm, wr.w);
      if ((m >> 2) == j) {  // own rows: hk partials + k-diag
        const int k = m & 3;
        fma4(p0, xm, kt1v[0][k]);
        fma4(p1, xm, kt1v[1][k]);
        fma4(acc[k], xm, kdv[k]);
      }
    }
    // butterfly over the 4 j-lanes (lanes 4q..4q+3): full hk at every lane
#pragma unroll
    for (int mask = 1; mask <= 2; mask <<= 1) {
      p0.x += __shfl_xor(p0.x, mask); p0.y += __shfl_xor(p0.y, mask);
      p0.z += __shfl_xor(p0.z, mask); p0.w += __shfl_xor(p0.w, mask);
      p1.x += __shfl_xor(p1.x, mask); p1.y += __shfl_xor(p1.y, mask);
      p1.z += __shfl_xor(p1.z, mask); p1.w += __shfl_xor(p1.w, mask);
    }
    // epilogue + stores
#pragma unroll
    for (int r = 0; r < 4; ++r) {
      fma4(acc[r], p0, kt2v[0][r]);
      fma4(acc[r], p1, kt2v[1][r]);
      *reinterpret_cast<vf4*>(out + ((size_t)(4 * j + r) * TDIM + t) * SDIM + s0) =
          acc[r];
    }

    // ---- stage t+1 into buf[nxt], then prefetch t+2 ----
    if (tt + 1 < TT) {
#pragma unroll
      for (int k = 0; k < 4; ++k) x_lds[nxt][4 * j + k][qg] = xp[k];
      float v = fmaf(q1a, q2a, wbase);
      v = fmaf(q1b, q2b, v);
      if (bm == bn) v += 1.0f + qd;
      wq_lds[nxt][tid] = v;
      if (tt + 2 < TT) {
        const int tp = t + 2;
#pragma unroll
        for (int k = 0; k < 4; ++k)
          xp[k] = ld4(in + ((size_t)(4 * j + k) * TDIM + tp) * SDIM + s0);
        q1a = qw1[tp * 32 + bm]; q1b = qw1[tp * 32 + 16 + bm];
        q2a = qw2[tp * 32 + bn]; q2b = qw2[tp * 32 + 16 + bn];
        qd = qdd[tp * 16 + bn];
      }
    }
    __syncthreads();
    cur = nxt;
  }
}

extern "C" void kernel_launch(void* const* d_in, const int* in_sizes, int n_in,
                              void* d_out, int out_size, void* d_ws, size_t ws_size,
                              hipStream_t stream) {
  const float* in = (const float*)d_in[0];
  const float* qw1 = (const float*)d_in[1];
  const float* qw2 = (const float*)d_in[2];
  const float* kw1 = (const float*)d_in[3];
  const float* kw2 = (const float*)d_in[4];
  const float* qdd = (const float*)d_in[5];
  const float* kdd = (const float*)d_in[6];
  const float* w = (const float*)d_in[7];
  float* out = (float*)d_out;
  float* ws = (float*)d_ws;

  const bool useKT = (ws_size >= 163840ull * sizeof(float));
  float* kt1 = ws;
  float* kt2 = ws + 65536;
  float* kddt = ws + 131072;

  dim3 grid(SDIM / SBLK, TDIM / TT);  // (8, 256)
  if (useKT) {
    hipLaunchKernelGGL(chp_prep, dim3(640), dim3(256), 0, stream, kw1, kw2, kdd, kt1,
                       kt2, kddt);
    hipLaunchKernelGGL((chp_main<true>), grid, dim3(256), 0, stream, in, w, qw1, qw2,
                       qdd, kw1, kw2, kdd, kt1, kt2, kddt, out);
  } else {
    hipLaunchKernelGGL((chp_main<false>), grid, dim3(256), 0, stream, in, w, qw1, qw2,
                       qdd, kw1, kw2, kdd, nullptr, nullptr, nullptr, out);
  }
}

// Round 7
// 153.120 us; speedup vs baseline: 1.1064x; 1.0220x over previous
//
#include <hip/hip_runtime.h>

// CrossHeadProjectionV2: B=1, N=16, T=S=2048, G=1, I=2, M=16.
// out[n,t,s] = sum_m x[m,t,s]*wq[t][m][n]
//            + sum_i kw2[s,i,n] * (sum_m x[m,t,s]*kw1[s,i,m])
//            + x[n,t,s]*kdd[s,n]
// wq folds w+I, qdd diagonal, and the rank-2 q-side update (t-only deps).
//
// R7 = R6 with ONE change: __syncthreads() -> {s_waitcnt lgkmcnt(0); s_barrier}.
// __syncthreads emits s_waitcnt vmcnt(0) before s_barrier, which drains the
// t+2 register prefetch every iteration (the guide's ~20% barrier-drain stall,
// here ~70%). Raw barrier + lgkmcnt-only drain keeps global loads in flight
// across the barrier (T3/T4 principle); double-buffered LDS makes lgkmcnt(0)
// sufficient for cross-wave correctness.

#define TDIM 2048
#define SDIM 2048
#define TT 8
#define SBLK 256

typedef float vf4 __attribute__((ext_vector_type(4)));

__device__ __forceinline__ void barrier_nodrain() {
  // Drain DS ops only (LDS handoff); leave vmcnt (global prefetch) in flight.
  asm volatile("s_waitcnt lgkmcnt(0)" ::: "memory");
  __builtin_amdgcn_s_barrier();
  asm volatile("" ::: "memory");
}

// ---- prep: transpose per-s weights to s-minor for coalesced reads ----
// kt1[i*16+m][s] = kw1[s][i][m]; kt2[i*16+n][s] = kw2[s][i][n]; kddt[n][s] = kdd[s][n]
__global__ void chp_prep(const float* __restrict__ kw1, const float* __restrict__ kw2,
                         const float* __restrict__ kdd,
                         float* __restrict__ kt1, float* __restrict__ kt2,
                         float* __restrict__ kddt) {
  int tid = blockIdx.x * blockDim.x + threadIdx.x;  // 0 .. 163839
  if (tid < 65536) {
    int im = tid >> 11, s = tid & 2047;
    kt1[tid] = kw1[s * 32 + im];
  } else if (tid < 131072) {
    int v = tid - 65536;
    int im = v >> 11, s = v & 2047;
    kt2[v] = kw2[s * 32 + im];
  } else if (tid < 163840) {
    int v = tid - 131072;
    int n = v >> 11, s = v & 2047;
    kddt[v] = kdd[s * 16 + n];
  }
}

__device__ __forceinline__ vf4 ld4(const float* p) {
  return *reinterpret_cast<const vf4*>(p);
}
__device__ __forceinline__ void fma4(vf4& d, const vf4& a, const vf4& b) {
  d.x = fmaf(a.x, b.x, d.x); d.y = fmaf(a.y, b.y, d.y);
  d.z = fmaf(a.z, b.z, d.z); d.w = fmaf(a.w, b.w, d.w);
}
__device__ __forceinline__ void fma4s(vf4& d, const vf4& a, float b) {
  d.x = fmaf(a.x, b, d.x); d.y = fmaf(a.y, b, d.y);
  d.z = fmaf(a.z, b, d.z); d.w = fmaf(a.w, b, d.w);
}

template <bool KT>
__global__ __launch_bounds__(256, 2) void chp_main(
    const float* __restrict__ in, const float* __restrict__ w,
    const float* __restrict__ qw1, const float* __restrict__ qw2,
    const float* __restrict__ qdd, const float* __restrict__ kw1,
    const float* __restrict__ kw2, const float* __restrict__ kdd,
    const float* __restrict__ kt1, const float* __restrict__ kt2,
    const float* __restrict__ kddt, float* __restrict__ out) {
  // x_lds[buf][m][quad], rows padded to 65 quads to break bank alignment.
  __shared__ vf4 x_lds[2][16][65];
  __shared__ float wq_lds[2][256];

  const int tid = threadIdx.x;
  const int j = tid & 3;        // n-slot: owns n,m in {4j..4j+3}
  const int qg = tid >> 2;      // s-quad within block: 0..63
  const int s0 = blockIdx.x * SBLK + qg * 4;
  const int t0 = blockIdx.y * TT;

  // ---- per-block register weights (own 4 rows, own s-quad) ----
  vf4 kt1v[2][4], kt2v[2][4], kdv[4];
  if constexpr (KT) {
#pragma unroll
    for (int i = 0; i < 2; ++i)
#pragma unroll
      for (int k = 0; k < 4; ++k) {
        kt1v[i][k] = ld4(kt1 + (size_t)(i * 16 + 4 * j + k) * SDIM + s0);
        kt2v[i][k] = ld4(kt2 + (size_t)(i * 16 + 4 * j + k) * SDIM + s0);
      }
#pragma unroll
    for (int k = 0; k < 4; ++k) kdv[k] = ld4(kddt + (size_t)(4 * j + k) * SDIM + s0);
  } else {
#pragma unroll
    for (int i = 0; i < 2; ++i)
#pragma unroll
      for (int k = 0; k < 4; ++k)
#pragma unroll
        for (int c = 0; c < 4; ++c) {
          kt1v[i][k][c] = kw1[(size_t)(s0 + c) * 32 + i * 16 + 4 * j + k];
          kt2v[i][k][c] = kw2[(size_t)(s0 + c) * 32 + i * 16 + 4 * j + k];
        }
#pragma unroll
    for (int k = 0; k < 4; ++k)
#pragma unroll
      for (int c = 0; c < 4; ++c) kdv[k][c] = kdd[(size_t)(s0 + c) * 16 + 4 * j + k];
  }

  // wq-build role of this thread: entry (bm, bn)
  const int bm = tid >> 4, bn = tid & 15;
  const float wbase = w[bm * 16 + bn];

  // ---- prologue: prefetch + stage t0, prefetch t0+1 ----
  vf4 xp[4];
#pragma unroll
  for (int k = 0; k < 4; ++k)
    xp[k] = ld4(in + ((size_t)(4 * j + k) * TDIM + t0) * SDIM + s0);
  float q1a = qw1[t0 * 32 + bm], q1b = qw1[t0 * 32 + 16 + bm];
  float q2a = qw2[t0 * 32 + bn], q2b = qw2[t0 * 32 + 16 + bn];
  float qd = qdd[t0 * 16 + bn];

#pragma unroll
  for (int k = 0; k < 4; ++k) x_lds[0][4 * j + k][qg] = xp[k];
  {
    float v = fmaf(q1a, q2a, wbase);
    v = fmaf(q1b, q2b, v);
    if (bm == bn) v += 1.0f + qd;
    wq_lds[0][tid] = v;
  }
  {  // prefetch t0+1
    const int t1 = t0 + 1;
#pragma unroll
    for (int k = 0; k < 4; ++k)
      xp[k] = ld4(in + ((size_t)(4 * j + k) * TDIM + t1) * SDIM + s0);
    q1a = qw1[t1 * 32 + bm]; q1b = qw1[t1 * 32 + 16 + bm];
    q2a = qw2[t1 * 32 + bn]; q2b = qw2[t1 * 32 + 16 + bn];
    qd = qdd[t1 * 16 + bn];
  }
  barrier_nodrain();

  int cur = 0;
  for (int tt = 0; tt < TT; ++tt) {
    const int t = t0 + tt;
    const int nxt = cur ^ 1;

    // ---- compute t from LDS buf[cur] ----
    vf4 acc[4];
    vf4 p0 = (vf4){0.f, 0.f, 0.f, 0.f}, p1 = p0;
#pragma unroll
    for (int r = 0; r < 4; ++r) acc[r] = (vf4){0.f, 0.f, 0.f, 0.f};

#pragma unroll
    for (int m = 0; m < 16; ++m) {
      const vf4 xm = x_lds[cur][m][qg];
      const vf4 wr = *reinterpret_cast<const vf4*>(&wq_lds[cur][m * 16 + 4 * j]);
      fma4s(acc[0], xm, wr.x);
      fma4s(acc[1], xm, wr.y);
      fma4s(acc[2], xm, wr.z);
      fma4s(acc[3], xm, wr.w);
      if ((m >> 2) == j) {  // own rows: hk partials + k-diag
        const int k = m & 3;
        fma4(p0, xm, kt1v[0][k]);
        fma4(p1, xm, kt1v[1][k]);
        fma4(acc[k], xm, kdv[k]);
      }
    }
    // butterfly over the 4 j-lanes (lanes 4q..4q+3): full hk at every lane
#pragma unroll
    for (int mask = 1; mask <= 2; mask <<= 1) {
      p0.x += __shfl_xor(p0.x, mask); p0.y += __shfl_xor(p0.y, mask);
      p0.z += __shfl_xor(p0.z, mask); p0.w += __shfl_xor(p0.w, mask);
      p1.x += __shfl_xor(p1.x, mask); p1.y += __shfl_xor(p1.y, mask);
      p1.z += __shfl_xor(p1.z, mask); p1.w += __shfl_xor(p1.w, mask);
    }
    // epilogue + stores
#pragma unroll
    for (int r = 0; r < 4; ++r) {
      fma4(acc[r], p0, kt2v[0][r]);
      fma4(acc[r], p1, kt2v[1][r]);
      *reinterpret_cast<vf4*>(out + ((size_t)(4 * j + r) * TDIM + t) * SDIM + s0) =
          acc[r];
    }

    // ---- stage t+1 into buf[nxt], then prefetch t+2 ----
    if (tt + 1 < TT) {
#pragma unroll
      for (int k = 0; k < 4; ++k) x_lds[nxt][4 * j + k][qg] = xp[k];
      float v = fmaf(q1a, q2a, wbase);
      v = fmaf(q1b, q2b, v);
      if (bm == bn) v += 1.0f + qd;
      wq_lds[nxt][tid] = v;
      if (tt + 2 < TT) {
        const int tp = t + 2;
#pragma unroll
        for (int k = 0; k < 4; ++k)
          xp[k] = ld4(in + ((size_t)(4 * j + k) * TDIM + tp) * SDIM + s0);
        q1a = qw1[tp * 32 + bm]; q1b = qw1[tp * 32 + 16 + bm];
        q2a = qw2[tp * 32 + bn]; q2b = qw2[tp * 32 + 16 + bn];
        qd = qdd[tp * 16 + bn];
      }
    }
    // DS handoff drained; global prefetch for t+2 stays in flight.
    barrier_nodrain();
    cur = nxt;
  }
}

extern "C" void kernel_launch(void* const* d_in, const int* in_sizes, int n_in,
                              void* d_out, int out_size, void* d_ws, size_t ws_size,
                              hipStream_t stream) {
  const float* in = (const float*)d_in[0];
  const float* qw1 = (const float*)d_in[1];
  const float* qw2 = (const float*)d_in[2];
  const float* kw1 = (const float*)d_in[3];
  const float* kw2 = (const float*)d_in[4];
  const float* qdd = (const float*)d_in[5];
  const float* kdd = (const float*)d_in[6];
  const float* w = (const float*)d_in[7];
  float* out = (float*)d_out;
  float* ws = (float*)d_ws;

  const bool useKT = (ws_size >= 163840ull * sizeof(float));
  float* kt1 = ws;
  float* kt2 = ws + 65536;
  float* kddt = ws + 131072;

  dim3 grid(SDIM / SBLK, TDIM / TT);  // (8, 256)
  if (useKT) {
    hipLaunchKernelGGL(chp_prep, dim3(640), dim3(256), 0, stream, kw1, kw2, kdd, kt1,
                       kt2, kddt);
    hipLaunchKernelGGL((chp_main<true>), grid, dim3(256), 0, stream, in, w, qw1, qw2,
                       qdd, kw1, kw2, kdd, kt1, kt2, kddt, out);
  } else {
    hipLaunchKernelGGL((chp_main<false>), grid, dim3(256), 0, stream, in, w, qw1, qw2,
                       qdd, kw1, kw2, kdd, nullptr, nullptr, nullptr, out);
  }
}

// Round 8
// 140.877 us; speedup vs baseline: 1.2025x; 1.0869x over previous
//
#include <hip/hip_runtime.h>

// CrossHeadProjectionV2: B=1, N=16, T=S=2048, G=1, I=2, M=16.
// out[n,t,s] = sum_m x[m,t,s]*wq[t][m][n]
//            + sum_i kw2[s,i,n] * (sum_m x[m,t,s]*kw1[s,i,m])
//            + x[n,t,s]*kdd[s,n]
// wq folds w+I, qdd diagonal, and the rank-2 q-side update (t-only deps).
//
// R8 = R7 with ONE change: the 20 vf4 of k-side weights are PINNED into
// VGPRs via opaque asm after their one-time load. R4/R6/R7 all showed
// VGPR_Count=84 — the allocator was rematerializing ~20 L2 loads per thread
// per t-iteration (~1.3 GB of hidden L2 traffic + exposed latency at 2.3
// waves/SIMD). The pin makes the loaded values opaque so rematerialization
// is impossible; expected VGPR ~164, same occupancy (8 waves/CU).

#define TDIM 2048
#define SDIM 2048
#define TT 8
#define SBLK 256

typedef float vf4 __attribute__((ext_vector_type(4)));

__device__ __forceinline__ void barrier_nodrain() {
  // Drain DS ops only (LDS handoff); leave vmcnt (global prefetch) in flight.
  asm volatile("s_waitcnt lgkmcnt(0)" ::: "memory");
  __builtin_amdgcn_s_barrier();
  asm volatile("" ::: "memory");
}

// Opaque pin: forces v's components to live in VGPRs; the compiler can no
// longer rematerialize the load that produced them.
__device__ __forceinline__ void pin4(vf4& v) {
  float a = v.x, b = v.y, c = v.z, d = v.w;
  asm volatile("" : "+v"(a), "+v"(b), "+v"(c), "+v"(d));
  v.x = a; v.y = b; v.z = c; v.w = d;
}

// ---- prep: transpose per-s weights to s-minor for coalesced reads ----
// kt1[i*16+m][s] = kw1[s][i][m]; kt2[i*16+n][s] = kw2[s][i][n]; kddt[n][s] = kdd[s][n]
__global__ void chp_prep(const float* __restrict__ kw1, const float* __restrict__ kw2,
                         const float* __restrict__ kdd,
                         float* __restrict__ kt1, float* __restrict__ kt2,
                         float* __restrict__ kddt) {
  int tid = blockIdx.x * blockDim.x + threadIdx.x;  // 0 .. 163839
  if (tid < 65536) {
    int im = tid >> 11, s = tid & 2047;
    kt1[tid] = kw1[s * 32 + im];
  } else if (tid < 131072) {
    int v = tid - 65536;
    int im = v >> 11, s = v & 2047;
    kt2[v] = kw2[s * 32 + im];
  } else if (tid < 163840) {
    int v = tid - 131072;
    int n = v >> 11, s = v & 2047;
    kddt[v] = kdd[s * 16 + n];
  }
}

__device__ __forceinline__ vf4 ld4(const float* p) {
  return *reinterpret_cast<const vf4*>(p);
}
__device__ __forceinline__ void fma4(vf4& d, const vf4& a, const vf4& b) {
  d.x = fmaf(a.x, b.x, d.x); d.y = fmaf(a.y, b.y, d.y);
  d.z = fmaf(a.z, b.z, d.z); d.w = fmaf(a.w, b.w, d.w);
}
__device__ __forceinline__ void fma4s(vf4& d, const vf4& a, float b) {
  d.x = fmaf(a.x, b, d.x); d.y = fmaf(a.y, b, d.y);
  d.z = fmaf(a.z, b, d.z); d.w = fmaf(a.w, b, d.w);
}

template <bool KT>
__global__ __launch_bounds__(256, 2) void chp_main(
    const float* __restrict__ in, const float* __restrict__ w,
    const float* __restrict__ qw1, const float* __restrict__ qw2,
    const float* __restrict__ qdd, const float* __restrict__ kw1,
    const float* __restrict__ kw2, const float* __restrict__ kdd,
    const float* __restrict__ kt1, const float* __restrict__ kt2,
    const float* __restrict__ kddt, float* __restrict__ out) {
  // x_lds[buf][m][quad], rows padded to 65 quads to break bank alignment.
  __shared__ vf4 x_lds[2][16][65];
  __shared__ float wq_lds[2][256];

  const int tid = threadIdx.x;
  const int j = tid & 3;        // n-slot: owns n,m in {4j..4j+3}
  const int qg = tid >> 2;      // s-quad within block: 0..63
  const int s0 = blockIdx.x * SBLK + qg * 4;
  const int t0 = blockIdx.y * TT;

  // ---- per-block register weights (own 4 rows, own s-quad), loaded ONCE ----
  vf4 kt1v[2][4], kt2v[2][4], kdv[4];
  if constexpr (KT) {
#pragma unroll
    for (int i = 0; i < 2; ++i)
#pragma unroll
      for (int k = 0; k < 4; ++k) {
        kt1v[i][k] = ld4(kt1 + (size_t)(i * 16 + 4 * j + k) * SDIM + s0);
        kt2v[i][k] = ld4(kt2 + (size_t)(i * 16 + 4 * j + k) * SDIM + s0);
      }
#pragma unroll
    for (int k = 0; k < 4; ++k) kdv[k] = ld4(kddt + (size_t)(4 * j + k) * SDIM + s0);
  } else {
#pragma unroll
    for (int i = 0; i < 2; ++i)
#pragma unroll
      for (int k = 0; k < 4; ++k)
#pragma unroll
        for (int c = 0; c < 4; ++c) {
          kt1v[i][k][c] = kw1[(size_t)(s0 + c) * 32 + i * 16 + 4 * j + k];
          kt2v[i][k][c] = kw2[(size_t)(s0 + c) * 32 + i * 16 + 4 * j + k];
        }
#pragma unroll
    for (int k = 0; k < 4; ++k)
#pragma unroll
      for (int c = 0; c < 4; ++c) kdv[k][c] = kdd[(size_t)(s0 + c) * 16 + 4 * j + k];
  }
  // PIN: make the weight values opaque so they stay register-resident.
#pragma unroll
  for (int i = 0; i < 2; ++i)
#pragma unroll
    for (int k = 0; k < 4; ++k) { pin4(kt1v[i][k]); pin4(kt2v[i][k]); }
#pragma unroll
  for (int k = 0; k < 4; ++k) pin4(kdv[k]);

  // wq-build role of this thread: entry (bm, bn)
  const int bm = tid >> 4, bn = tid & 15;
  const float wbase = w[bm * 16 + bn];

  // ---- prologue: prefetch + stage t0, prefetch t0+1 ----
  vf4 xp[4];
#pragma unroll
  for (int k = 0; k < 4; ++k)
    xp[k] = ld4(in + ((size_t)(4 * j + k) * TDIM + t0) * SDIM + s0);
  float q1a = qw1[t0 * 32 + bm], q1b = qw1[t0 * 32 + 16 + bm];
  float q2a = qw2[t0 * 32 + bn], q2b = qw2[t0 * 32 + 16 + bn];
  float qd = qdd[t0 * 16 + bn];

#pragma unroll
  for (int k = 0; k < 4; ++k) x_lds[0][4 * j + k][qg] = xp[k];
  {
    float v = fmaf(q1a, q2a, wbase);
    v = fmaf(q1b, q2b, v);
    if (bm == bn) v += 1.0f + qd;
    wq_lds[0][tid] = v;
  }
  {  // prefetch t0+1
    const int t1 = t0 + 1;
#pragma unroll
    for (int k = 0; k < 4; ++k)
      xp[k] = ld4(in + ((size_t)(4 * j + k) * TDIM + t1) * SDIM + s0);
    q1a = qw1[t1 * 32 + bm]; q1b = qw1[t1 * 32 + 16 + bm];
    q2a = qw2[t1 * 32 + bn]; q2b = qw2[t1 * 32 + 16 + bn];
    qd = qdd[t1 * 16 + bn];
  }
  barrier_nodrain();

  int cur = 0;
  for (int tt = 0; tt < TT; ++tt) {
    const int t = t0 + tt;
    const int nxt = cur ^ 1;

    // ---- compute t from LDS buf[cur] ----
    vf4 acc[4];
    vf4 p0 = (vf4){0.f, 0.f, 0.f, 0.f}, p1 = p0;
#pragma unroll
    for (int r = 0; r < 4; ++r) acc[r] = (vf4){0.f, 0.f, 0.f, 0.f};

#pragma unroll
    for (int m = 0; m < 16; ++m) {
      const vf4 xm = x_lds[cur][m][qg];
      const vf4 wr = *reinterpret_cast<const vf4*>(&wq_lds[cur][m * 16 + 4 * j]);
      fma4s(acc[0], xm, wr.x);
      fma4s(acc[1], xm, wr.y);
      fma4s(acc[2], xm, wr.z);
      fma4s(acc[3], xm, wr.w);
      if ((m >> 2) == j) {  // own rows: hk partials + k-diag
        const int k = m & 3;
        fma4(p0, xm, kt1v[0][k]);
        fma4(p1, xm, kt1v[1][k]);
        fma4(acc[k], xm, kdv[k]);
      }
    }
    // butterfly over the 4 j-lanes (lanes 4q..4q+3): full hk at every lane
#pragma unroll
    for (int mask = 1; mask <= 2; mask <<= 1) {
      p0.x += __shfl_xor(p0.x, mask); p0.y += __shfl_xor(p0.y, mask);
      p0.z += __shfl_xor(p0.z, mask); p0.w += __shfl_xor(p0.w, mask);
      p1.x += __shfl_xor(p1.x, mask); p1.y += __shfl_xor(p1.y, mask);
      p1.z += __shfl_xor(p1.z, mask); p1.w += __shfl_xor(p1.w, mask);
    }
    // epilogue + stores
#pragma unroll
    for (int r = 0; r < 4; ++r) {
      fma4(acc[r], p0, kt2v[0][r]);
      fma4(acc[r], p1, kt2v[1][r]);
      *reinterpret_cast<vf4*>(out + ((size_t)(4 * j + r) * TDIM + t) * SDIM + s0) =
          acc[r];
    }

    // ---- stage t+1 into buf[nxt], then prefetch t+2 ----
    if (tt + 1 < TT) {
#pragma unroll
      for (int k = 0; k < 4; ++k) x_lds[nxt][4 * j + k][qg] = xp[k];
      float v = fmaf(q1a, q2a, wbase);
      v = fmaf(q1b, q2b, v);
      if (bm == bn) v += 1.0f + qd;
      wq_lds[nxt][tid] = v;
      if (tt + 2 < TT) {
        const int tp = t + 2;
#pragma unroll
        for (int k = 0; k < 4; ++k)
          xp[k] = ld4(in + ((size_t)(4 * j + k) * TDIM + tp) * SDIM + s0);
        q1a = qw1[tp * 32 + bm]; q1b = qw1[tp * 32 + 16 + bm];
        q2a = qw2[tp * 32 + bn]; q2b = qw2[tp * 32 + 16 + bn];
        qd = qdd[tp * 16 + bn];
      }
    }
    // DS handoff drained; global prefetch for t+2 stays in flight.
    barrier_nodrain();
    cur = nxt;
  }
}

extern "C" void kernel_launch(void* const* d_in, const int* in_sizes, int n_in,
                              void* d_out, int out_size, void* d_ws, size_t ws_size,
                              hipStream_t stream) {
  const float* in = (const float*)d_in[0];
  const float* qw1 = (const float*)d_in[1];
  const float* qw2 = (const float*)d_in[2];
  const float* kw1 = (const float*)d_in[3];
  const float* kw2 = (const float*)d_in[4];
  const float* qdd = (const float*)d_in[5];
  const float* kdd = (const float*)d_in[6];
  const float* w = (const float*)d_in[7];
  float* out = (float*)d_out;
  float* ws = (float*)d_ws;

  const bool useKT = (ws_size >= 163840ull * sizeof(float));
  float* kt1 = ws;
  float* kt2 = ws + 65536;
  float* kddt = ws + 131072;

  dim3 grid(SDIM / SBLK, TDIM / TT);  // (8, 256)
  if (useKT) {
    hipLaunchKernelGGL(chp_prep, dim3(640), dim3(256), 0, stream, kw1, kw2, kdd, kt1,
                       kt2, kddt);
    hipLaunchKernelGGL((chp_main<true>), grid, dim3(256), 0, stream, in, w, qw1, qw2,
                       qdd, kw1, kw2, kdd, kt1, kt2, kddt, out);
  } else {
    hipLaunchKernelGGL((chp_main<false>), grid, dim3(256), 0, stream, in, w, qw1, qw2,
                       qdd, kw1, kw2, kdd, nullptr, nullptr, nullptr, out);
  }
}